// Round 12
// baseline (4768.309 us; speedup 1.0000x reference)
//
#include <hip/hip_runtime.h>
#include <math.h>

#define T_ 512
#define B_ 64
#define H_ 512
#define D_ 32
#define G7H (7*H_)          // 3584
#define NBLK 128
#define NTHR 256            // 4 waves; wave = m-tile, FULL K per wave
#define JPB 4               // hidden channels (j) per block -> 32 cols (4 pad)
#define BH (B_*H_)

typedef _Float16 f16x8 __attribute__((ext_vector_type(8)));
typedef float f32x4  __attribute__((ext_vector_type(4)));
typedef int   i32x4  __attribute__((ext_vector_type(4)));

// ---- P2[type][j][gate(8)] = b_gates + embed@W_x  (pad gate 7 = 0), exact f32 ----
__global__ void precompute_P2(const float* __restrict__ embed,
                              const float* __restrict__ Wg,
                              const float* __restrict__ bg,
                              float* __restrict__ P2) {
    int idx = blockIdx.x * blockDim.x + threadIdx.x;
    if (idx >= 33 * H_ * 8) return;
    int gate = idx & 7;
    int j    = (idx >> 3) & (H_ - 1);
    int type = idx >> 12;
    float acc = 0.f;
    if (gate < 7) {
        acc = bg[gate * H_ + j];
        #pragma unroll
        for (int d = 0; d < D_; ++d)
            acc += embed[type * D_ + d] * Wg[(size_t)d * G7H + gate * H_ + j];
    }
    P2[idx] = acc;
}

// ---- Wt16[n][k] = fp16(W_h^T) ----
__global__ void precompute_Wt16(const float* __restrict__ Wg,
                                _Float16* __restrict__ Wt) {
    int idx = blockIdx.x * blockDim.x + threadIdx.x;   // n*512 + k
    if (idx >= G7H * H_) return;
    int k = idx & (H_ - 1);
    int n = idx >> 9;
    Wt[idx] = (_Float16)Wg[(size_t)(D_ + k) * G7H + n];
}

// ---- h buffer 0 init (fp16) ----
__global__ void init_h16(const float* __restrict__ h0, _Float16* __restrict__ hf) {
    int idx = blockIdx.x * blockDim.x + threadIdx.x;
    if (idx >= BH) return;
    hf[idx] = (_Float16)h0[idx];
}

__device__ __forceinline__ float fast_rcp(float x) {
    float r;
    asm("v_rcp_f32 %0, %1" : "=v"(r) : "v"(x));
    return r;
}
__device__ __forceinline__ float fast_sigmoid(float x) {
    return fast_rcp(1.f + __expf(-x));
}
__device__ __forceinline__ float fast_tanh(float x) {
    return 1.f - 2.f * fast_rcp(1.f + __expf(2.f * x));
}

// per-step A loads (sc1 = L3-coherent), pipelined 16B
#define LOADA(dst, p, OFF) \
    asm volatile("global_load_dwordx4 %0, %1, off offset:" #OFF " sc1" \
                 : "=v"(dst) : "v"(p) : "memory")

// issue 2x dwordx4 flag loads (covers this lane's 8 of 512 flags), NO wait
#define LOADF(v0, v1, p) \
    asm volatile("global_load_dwordx4 %0, %2, off sc1\n\t" \
                 "global_load_dwordx4 %1, %2, off offset:16 sc1" \
                 : "=&v"(v0), "=&v"(v1) : "v"(p) : "memory")

// ---------------- persistent recurrent kernel: 0 barriers, per-wave flags ----------------
__global__ void __launch_bounds__(NTHR, 1)
hawkes_main(const float* __restrict__ seq_dt, const int* __restrict__ seq_types,
            const float* __restrict__ c0, const float* __restrict__ ct0,
            const float* __restrict__ P2,
            const _Float16* __restrict__ Wt,
            _Float16* __restrict__ hf,     // 2 x (B_*H_) fp16 double buffer
            int* __restrict__ flags,       // 512 ints: [wave][bid], monotonic
            float* __restrict__ out) {
    __shared__ float gl[B_][36];        // in-wave g transpose only (9 KB)

    const int tid  = threadIdx.x;
    const int w    = tid >> 6;          // wave = m-tile (b-range), full K
    const int lane = tid & 63;
    const int bid  = blockIdx.x;
    const int j0   = (bid & 7) * 64 + (bid >> 3) * JPB;   // XCD-grouped j
    const int m0   = w * 16;
    const int krow = (lane >> 4) << 3;

    // ---- one-time: W fragments, plain loads, MFMA-only use (AGPR-friendly) ----
    f16x8 Bf[2][16];
    {
        const f16x8 zf = {0, 0, 0, 0, 0, 0, 0, 0};
        #pragma unroll
        for (int nt = 0; nt < 2; ++nt) {
            const int cl = nt * 16 + (lane & 15);
            const int gate = cl & 7, jl2 = cl >> 3;
            const bool pad = (gate == 7);
            const size_t nb = pad ? 0 : (size_t)(gate * H_ + j0 + jl2) * (size_t)H_;
            #pragma unroll
            for (int kt = 0; kt < 16; ++kt) {
                f16x8 v = *(const f16x8*)(Wt + nb + kt * 32 + krow);
                Bf[nt][kt] = pad ? zf : v;
            }
        }
    }

    // ---- cell ownership: 256 threads, 1 cell each; wave w owns rows m0..m0+15 ----
    const int eb = tid >> 2, ejl = tid & 3, ej = j0 + ejl;
    float c_s  = c0 [eb * H_ + ej];
    float ct_s = ct0[eb * H_ + ej];

    int   typ = seq_types[eb];
    float dtv = seq_dt[eb];
    float4 pa, pb;
    {
        const float* pr = P2 + ((size_t)typ * H_ + ej) * 8;
        pa = *(const float4*)pr;
        pb = *(const float4*)(pr + 4);
    }

    const size_t TBH = (size_t)T_ * BH;
    const int arow = m0 + (lane & 15);
    int* const myflag = flags + w * NBLK + bid;
    const int* const fp = flags + lane * 8;

    for (int t = 0; t < T_; ++t) {
        // ---- A-fragments: 16 pipelined 16B sc1 loads (full K row slice) ----
        const _Float16* ph = hf + (t & 1) * BH + arow * H_ + krow;
        f16x8 Af[16];
        LOADA(Af[0],  ph, 0);    LOADA(Af[1],  ph, 64);
        LOADA(Af[2],  ph, 128);  LOADA(Af[3],  ph, 192);
        LOADA(Af[4],  ph, 256);  LOADA(Af[5],  ph, 320);
        LOADA(Af[6],  ph, 384);  LOADA(Af[7],  ph, 448);
        LOADA(Af[8],  ph, 512);  LOADA(Af[9],  ph, 576);
        LOADA(Af[10], ph, 640);  LOADA(Af[11], ph, 704);
        LOADA(Af[12], ph, 768);  LOADA(Af[13], ph, 832);
        LOADA(Af[14], ph, 896);  LOADA(Af[15], ph, 960);
        asm volatile("s_waitcnt vmcnt(0)" ::: "memory");
        __builtin_amdgcn_sched_barrier(0);

        // ---- 4 interleaved MFMA chains ----
        f32x4 a0a = {0.f,0.f,0.f,0.f}, a0b = {0.f,0.f,0.f,0.f};
        f32x4 a1a = {0.f,0.f,0.f,0.f}, a1b = {0.f,0.f,0.f,0.f};
        #pragma unroll
        for (int kt = 0; kt < 16; kt += 2) {
            a0a = __builtin_amdgcn_mfma_f32_16x16x32_f16(Af[kt],     Bf[0][kt],     a0a, 0, 0, 0);
            a1a = __builtin_amdgcn_mfma_f32_16x16x32_f16(Af[kt],     Bf[1][kt],     a1a, 0, 0, 0);
            a0b = __builtin_amdgcn_mfma_f32_16x16x32_f16(Af[kt + 1], Bf[0][kt + 1], a0b, 0, 0, 0);
            a1b = __builtin_amdgcn_mfma_f32_16x16x32_f16(Af[kt + 1], Bf[1][kt + 1], a1b, 0, 0, 0);
        }
        const f32x4 a0 = a0a + a0b, a1 = a1a + a1b;

        // ---- in-wave transpose via gl (writer wave == reader wave) ----
        {
            const int col = lane & 15, rbase = m0 + ((lane >> 4) << 2);
            #pragma unroll
            for (int r = 0; r < 4; ++r) {
                gl[rbase + r][col]      = a0[r];
                gl[rbase + r][16 + col] = a1[r];
            }
        }
        asm volatile("s_waitcnt lgkmcnt(0)" ::: "memory");
        __builtin_amdgcn_sched_barrier(0);

        // ---- elementwise: 1 cell per thread (wave-local rows) ----
        float4 ga = *(const float4*)&gl[eb][ejl * 8];
        float4 gb = *(const float4*)&gl[eb][ejl * 8 + 4];
        const float g0 = ga.x + pa.x, g1 = ga.y + pa.y, g2 = ga.z + pa.z, g3 = ga.w + pa.w;
        const float g4 = gb.x + pb.x, g5 = gb.y + pb.y, g6 = gb.z + pb.z;

        const float inpt   = fast_sigmoid(g0);
        const float forget = fast_sigmoid(g1);
        const float outp   = fast_sigmoid(g2);
        const float in_tar = fast_sigmoid(g3);
        const float fg_tar = fast_sigmoid(g4);
        const float z      = fast_tanh(g5);
        const float y      = 10.f * g6;
        const float decay  = (fmaxf(y, 0.f) + __logf(1.f + __expf(-fabsf(y)))) * 0.1f;

        const float c_i      = forget * c_s + inpt * z;
        const float ctar_new = fg_tar * ct_s + in_tar * z;
        const float c_t = ctar_new + (c_i - ctar_new) * __expf(-decay * dtv);
        const float h_t = outp * fast_tanh(c_t);
        c_s  = c_t;
        ct_s = ctar_new;

        // ---- recurrent h (fp16), pairwise u32 agent-scope stores ----
        {
            union { _Float16 f; unsigned short u; } cv; cv.f = (_Float16)h_t;
            unsigned hs = cv.u;
            unsigned oh = (unsigned)__shfl_down((int)hs, 1);
            if ((ejl & 1) == 0) {
                unsigned* dh = (unsigned*)(hf + ((t + 1) & 1) * BH) + ((eb * H_ + ej) >> 1);
                __hip_atomic_store(dh, hs | (oh << 16), __ATOMIC_RELAXED, __HIP_MEMORY_SCOPE_AGENT);
            }
        }

        // ---- per-wave drain + wave-flag (NO barrier) ----
        asm volatile("s_waitcnt vmcnt(0)" ::: "memory");
        __builtin_amdgcn_sched_barrier(0);
        if (lane == 0)
            __hip_atomic_store(myflag, t + 1, __ATOMIC_RELAXED, __HIP_MEMORY_SCOPE_AGENT);

        if (t + 1 < T_) {
            // issue first flag-poll round BEFORE out-stores: store-drain overlaps flag RT
            i32x4 v0, v1;
            LOADF(v0, v1, fp);

            // out-stores + next-step prefetch (overlap the flag round trip)
            {
                const size_t base = (size_t)t * BH + (size_t)eb * H_ + ej;
                out[base]           = h_t;
                out[TBH + base]     = outp;
                out[2 * TBH + base] = c_i;
                out[3 * TBH + base] = ctar_new;
                out[4 * TBH + base] = decay;
            }
            typ = seq_types[(t + 1) * B_ + eb];
            dtv = seq_dt  [(t + 1) * B_ + eb];
            const float* pr = P2 + ((size_t)typ * H_ + ej) * 8;
            pa = *(const float4*)pr;
            pb = *(const float4*)(pr + 4);

            asm volatile("s_waitcnt vmcnt(0)" ::: "memory");
            int ok = (v0.x >= t + 1) && (v0.y >= t + 1) && (v0.z >= t + 1) && (v0.w >= t + 1) &&
                     (v1.x >= t + 1) && (v1.y >= t + 1) && (v1.z >= t + 1) && (v1.w >= t + 1);
            while (!__all(ok)) {
                LOADF(v0, v1, fp);
                asm volatile("s_waitcnt vmcnt(0)" ::: "memory");
                ok = (v0.x >= t + 1) && (v0.y >= t + 1) && (v0.z >= t + 1) && (v0.w >= t + 1) &&
                     (v1.x >= t + 1) && (v1.y >= t + 1) && (v1.z >= t + 1) && (v1.w >= t + 1);
            }
            __builtin_amdgcn_sched_barrier(0);
        } else {
            const size_t base = (size_t)t * BH + (size_t)eb * H_ + ej;
            out[base]           = h_t;
            out[TBH + base]     = outp;
            out[2 * TBH + base] = c_i;
            out[3 * TBH + base] = ctar_new;
            out[4 * TBH + base] = decay;
        }
    }
}

extern "C" void kernel_launch(void* const* d_in, const int* in_sizes, int n_in,
                              void* d_out, int out_size, void* d_ws, size_t ws_size,
                              hipStream_t stream) {
    const float* seq_dt    = (const float*)d_in[0];
    const int*   seq_types = (const int*)  d_in[1];
    const float* embed     = (const float*)d_in[2];
    const float* W_gates   = (const float*)d_in[3];
    const float* b_gates   = (const float*)d_in[4];
    const float* h0        = (const float*)d_in[5];
    const float* c0        = (const float*)d_in[6];
    const float* ct0       = (const float*)d_in[7];
    float* out = (float*)d_out;

    // workspace: P2 | Wt16 | hf(2 buf) | flags(512)
    float* P2 = (float*)d_ws;                              // 33*512*8 f32
    _Float16* Wt = (_Float16*)(P2 + 33 * H_ * 8);          // 3584*512 fp16
    _Float16* hf = Wt + (size_t)G7H * H_;                  // 2*B*H fp16
    int* flags = (int*)(hf + 2 * BH);

    hipMemsetAsync(flags, 0, 512 * sizeof(int), stream);
    {
        int total = 33 * H_ * 8;
        precompute_P2<<<(total + 255) / 256, 256, 0, stream>>>(embed, W_gates, b_gates, P2);
    }
    {
        int total = G7H * H_;
        precompute_Wt16<<<(total + 255) / 256, 256, 0, stream>>>(W_gates, Wt);
    }
    {
        int total = BH;
        init_h16<<<(total + 255) / 256, 256, 0, stream>>>(h0, hf);
    }
    {
        void* args[] = {(void*)&seq_dt, (void*)&seq_types, (void*)&c0, (void*)&ct0,
                        (void*)&P2, (void*)&Wt, (void*)&hf, (void*)&flags, (void*)&out};
        hipLaunchCooperativeKernel((void*)hawkes_main, dim3(NBLK), dim3(NTHR),
                                   args, 0, stream);
    }
}

// Round 14
// 1939.176 us; speedup vs baseline: 2.4589x; 2.4589x over previous
//
#include <hip/hip_runtime.h>
#include <math.h>

#define T_ 512
#define B_ 64
#define H_ 512
#define D_ 32
#define G7H (7*H_)          // 3584
#define NBLK 128
#define NTHR 256            // 4 waves; wave = m-tile, FULL K per wave
#define JPB 4               // hidden channels (j) per block -> 32 cols (4 pad)
#define BH (B_*H_)

typedef _Float16 f16x8 __attribute__((ext_vector_type(8)));
typedef float f32x4  __attribute__((ext_vector_type(4)));
typedef int   i32x2  __attribute__((ext_vector_type(2)));

// ---- P2[type][j][gate(8)] = b_gates + embed@W_x  (pad gate 7 = 0), exact f32 ----
__global__ void precompute_P2(const float* __restrict__ embed,
                              const float* __restrict__ Wg,
                              const float* __restrict__ bg,
                              float* __restrict__ P2) {
    int idx = blockIdx.x * blockDim.x + threadIdx.x;
    if (idx >= 33 * H_ * 8) return;
    int gate = idx & 7;
    int j    = (idx >> 3) & (H_ - 1);
    int type = idx >> 12;
    float acc = 0.f;
    if (gate < 7) {
        acc = bg[gate * H_ + j];
        #pragma unroll
        for (int d = 0; d < D_; ++d)
            acc += embed[type * D_ + d] * Wg[(size_t)d * G7H + gate * H_ + j];
    }
    P2[idx] = acc;
}

// ---- Wt16[n][k] = fp16(W_h^T) ----
__global__ void precompute_Wt16(const float* __restrict__ Wg,
                                _Float16* __restrict__ Wt) {
    int idx = blockIdx.x * blockDim.x + threadIdx.x;   // n*512 + k
    if (idx >= G7H * H_) return;
    int k = idx & (H_ - 1);
    int n = idx >> 9;
    Wt[idx] = (_Float16)Wg[(size_t)(D_ + k) * G7H + n];
}

// ---- h buffer 0 init (fp16) ----
__global__ void init_h16(const float* __restrict__ h0, _Float16* __restrict__ hf) {
    int idx = blockIdx.x * blockDim.x + threadIdx.x;
    if (idx >= BH) return;
    hf[idx] = (_Float16)h0[idx];
}

__device__ __forceinline__ float fast_rcp(float x) {
    float r;
    asm("v_rcp_f32 %0, %1" : "=v"(r) : "v"(x));
    return r;
}
__device__ __forceinline__ float fast_sigmoid(float x) {
    return fast_rcp(1.f + __expf(-x));
}
__device__ __forceinline__ float fast_tanh(float x) {
    return 1.f - 2.f * fast_rcp(1.f + __expf(2.f * x));
}

// per-step A loads (sc1 = L3-coherent), pipelined 16B
#define LOADA(dst, p, OFF) \
    asm volatile("global_load_dwordx4 %0, %1, off offset:" #OFF " sc1" \
                 : "=v"(dst) : "v"(p) : "memory")

// ---------------- persistent recurrent kernel (fp16 MFMA, no K-split) ----------------
__global__ void __launch_bounds__(NTHR, 1)
hawkes_main(const float* __restrict__ seq_dt, const int* __restrict__ seq_types,
            const float* __restrict__ c0, const float* __restrict__ ct0,
            const float* __restrict__ P2,
            const _Float16* __restrict__ Wt,
            _Float16* __restrict__ hf,     // 2 x (B_*H_) fp16 double buffer
            int* __restrict__ flags,       // NBLK ints, monotonic step counters
            float* __restrict__ out) {
    __shared__ float gl[B_][36];        // in-wave g transpose only (9 KB)

    const int tid  = threadIdx.x;
    const int w    = tid >> 6;          // wave = m-tile (b-range), full K
    const int lane = tid & 63;
    const int bid  = blockIdx.x;
    const int j0   = (bid & 7) * 64 + (bid >> 3) * JPB;   // XCD-grouped j
    const int m0   = w * 16;
    const int krow = (lane >> 4) << 3;

    // ---- one-time: W fragments, plain loads, MFMA-only use (AGPR-friendly) ----
    // block cols: c_local = jl*8 + gate (gate 7 = pad), 32 cols = 2 n-tiles
    f16x8 Bf[2][16];
    {
        const f16x8 zf = {0, 0, 0, 0, 0, 0, 0, 0};
        #pragma unroll
        for (int nt = 0; nt < 2; ++nt) {
            const int cl = nt * 16 + (lane & 15);
            const int gate = cl & 7, jl2 = cl >> 3;
            const bool pad = (gate == 7);
            const size_t nb = pad ? 0 : (size_t)(gate * H_ + j0 + jl2) * (size_t)H_;
            #pragma unroll
            for (int kt = 0; kt < 16; ++kt) {
                f16x8 v = *(const f16x8*)(Wt + nb + kt * 32 + krow);
                Bf[nt][kt] = pad ? zf : v;
            }
        }
    }

    // ---- cell ownership: 256 threads, 1 cell each (b=tid>>2, jl=tid&3) ----
    const int eb = tid >> 2, ejl = tid & 3, ej = j0 + ejl;
    float c_s  = c0 [eb * H_ + ej];
    float ct_s = ct0[eb * H_ + ej];

    // first-step scalars (later steps prefetch during the poll window)
    int   typ = seq_types[eb];
    float dtv = seq_dt[eb];
    float4 pa, pb;
    {
        const float* pr = P2 + ((size_t)typ * H_ + ej) * 8;
        pa = *(const float4*)pr;
        pb = *(const float4*)(pr + 4);
    }

    const size_t TBH = (size_t)T_ * BH;
    const int arow = m0 + (lane & 15);

    for (int t = 0; t < T_; ++t) {
        // ---- A-fragments: 16 pipelined 16B sc1 loads (full K row slice) ----
        const _Float16* ph = hf + (t & 1) * BH + arow * H_ + krow;
        f16x8 Af[16];
        LOADA(Af[0],  ph, 0);    LOADA(Af[1],  ph, 64);
        LOADA(Af[2],  ph, 128);  LOADA(Af[3],  ph, 192);
        LOADA(Af[4],  ph, 256);  LOADA(Af[5],  ph, 320);
        LOADA(Af[6],  ph, 384);  LOADA(Af[7],  ph, 448);
        LOADA(Af[8],  ph, 512);  LOADA(Af[9],  ph, 576);
        LOADA(Af[10], ph, 640);  LOADA(Af[11], ph, 704);
        LOADA(Af[12], ph, 768);  LOADA(Af[13], ph, 832);
        LOADA(Af[14], ph, 896);  LOADA(Af[15], ph, 960);
        asm volatile("s_waitcnt vmcnt(0)" ::: "memory");
        __builtin_amdgcn_sched_barrier(0);

        // ---- 4 interleaved MFMA chains (halve dependent latency) ----
        f32x4 a0a = {0.f,0.f,0.f,0.f}, a0b = {0.f,0.f,0.f,0.f};
        f32x4 a1a = {0.f,0.f,0.f,0.f}, a1b = {0.f,0.f,0.f,0.f};
        #pragma unroll
        for (int kt = 0; kt < 16; kt += 2) {
            a0a = __builtin_amdgcn_mfma_f32_16x16x32_f16(Af[kt],     Bf[0][kt],     a0a, 0, 0, 0);
            a1a = __builtin_amdgcn_mfma_f32_16x16x32_f16(Af[kt],     Bf[1][kt],     a1a, 0, 0, 0);
            a0b = __builtin_amdgcn_mfma_f32_16x16x32_f16(Af[kt + 1], Bf[0][kt + 1], a0b, 0, 0, 0);
            a1b = __builtin_amdgcn_mfma_f32_16x16x32_f16(Af[kt + 1], Bf[1][kt + 1], a1b, 0, 0, 0);
        }
        const f32x4 a0 = a0a + a0b, a1 = a1a + a1b;

        // ---- in-wave transpose via gl: writer wave == reader wave ----
        {
            const int col = lane & 15, rbase = m0 + ((lane >> 4) << 2);
            #pragma unroll
            for (int r = 0; r < 4; ++r) {
                gl[rbase + r][col]      = a0[r];
                gl[rbase + r][16 + col] = a1[r];
            }
        }
        asm volatile("s_waitcnt lgkmcnt(0)" ::: "memory");
        __builtin_amdgcn_sched_barrier(0);

        // ---- elementwise: 1 cell per thread ----
        float4 ga = *(const float4*)&gl[eb][ejl * 8];
        float4 gb = *(const float4*)&gl[eb][ejl * 8 + 4];
        const float g0 = ga.x + pa.x, g1 = ga.y + pa.y, g2 = ga.z + pa.z, g3 = ga.w + pa.w;
        const float g4 = gb.x + pb.x, g5 = gb.y + pb.y, g6 = gb.z + pb.z;

        const float inpt   = fast_sigmoid(g0);
        const float forget = fast_sigmoid(g1);
        const float outp   = fast_sigmoid(g2);
        const float in_tar = fast_sigmoid(g3);
        const float fg_tar = fast_sigmoid(g4);
        const float z      = fast_tanh(g5);
        const float y      = 10.f * g6;
        const float decay  = (fmaxf(y, 0.f) + __logf(1.f + __expf(-fabsf(y)))) * 0.1f;

        const float c_i      = forget * c_s + inpt * z;
        const float ctar_new = fg_tar * ct_s + in_tar * z;
        const float c_t = ctar_new + (c_i - ctar_new) * __expf(-decay * dtv);
        const float h_t = outp * fast_tanh(c_t);
        c_s  = c_t;
        ct_s = ctar_new;

        // ---- recurrent h (fp16), pairwise u32 agent-scope stores ----
        {
            union { _Float16 f; unsigned short u; } cv; cv.f = (_Float16)h_t;
            unsigned hs = cv.u;
            unsigned oh = (unsigned)__shfl_down((int)hs, 1);
            if ((ejl & 1) == 0) {
                unsigned* dh = (unsigned*)(hf + ((t + 1) & 1) * BH) + ((eb * H_ + ej) >> 1);
                __hip_atomic_store(dh, hs | (oh << 16), __ATOMIC_RELAXED, __HIP_MEMORY_SCOPE_AGENT);
            }
        }

        // ---- barrier #1: drain h stores (syncthreads emits vmcnt(0)), set flag ----
        __syncthreads();
        if (tid == 0)
            __hip_atomic_store(flags + bid, t + 1, __ATOMIC_RELAXED, __HIP_MEMORY_SCOPE_AGENT);

        // ---- output stores: fire-and-forget, overlap the poll ----
        {
            const size_t base = (size_t)t * BH + (size_t)eb * H_ + ej;
            out[base]           = h_t;
            out[TBH + base]     = outp;
            out[2 * TBH + base] = c_i;
            out[3 * TBH + base] = ctar_new;
            out[4 * TBH + base] = decay;
        }

        // ---- prefetch next step's scalars + P2 row (overlaps poll) ----
        {
            const int tn = (t + 1 < T_) ? t + 1 : t;
            typ = seq_types[tn * B_ + eb];
            dtv = seq_dt  [tn * B_ + eb];
            const float* pr = P2 + ((size_t)typ * H_ + ej) * 8;
            pa = *(const float4*)pr;
            pb = *(const float4*)(pr + 4);
        }

        // ---- wave0 polls all 128 flags; barrier #2 releases ----
        if (t + 1 < T_) {
            if (w == 0) {
                const int* fp = flags + 2 * lane;
                int ok;
                do {
                    i32x2 vv;
                    asm volatile("global_load_dwordx2 %0, %1, off sc1\n\t"
                                 "s_waitcnt vmcnt(0)"
                                 : "=&v"(vv) : "v"(fp) : "memory");
                    ok = (vv.x >= t + 1) && (vv.y >= t + 1);
                } while (!__all(ok));
            }
            __syncthreads();
        }
    }
}

extern "C" void kernel_launch(void* const* d_in, const int* in_sizes, int n_in,
                              void* d_out, int out_size, void* d_ws, size_t ws_size,
                              hipStream_t stream) {
    const float* seq_dt    = (const float*)d_in[0];
    const int*   seq_types = (const int*)  d_in[1];
    const float* embed     = (const float*)d_in[2];
    const float* W_gates   = (const float*)d_in[3];
    const float* b_gates   = (const float*)d_in[4];
    const float* h0        = (const float*)d_in[5];
    const float* c0        = (const float*)d_in[6];
    const float* ct0       = (const float*)d_in[7];
    float* out = (float*)d_out;

    // workspace: P2 | Wt16 | hf(2 buf) | flags
    float* P2 = (float*)d_ws;                              // 33*512*8 f32
    _Float16* Wt = (_Float16*)(P2 + 33 * H_ * 8);          // 3584*512 fp16
    _Float16* hf = Wt + (size_t)G7H * H_;                  // 2*B*H fp16
    int* flags = (int*)(hf + 2 * BH);

    hipMemsetAsync(flags, 0, NBLK * sizeof(int), stream);
    {
        int total = 33 * H_ * 8;
        precompute_P2<<<(total + 255) / 256, 256, 0, stream>>>(embed, W_gates, b_gates, P2);
    }
    {
        int total = G7H * H_;
        precompute_Wt16<<<(total + 255) / 256, 256, 0, stream>>>(W_gates, Wt);
    }
    {
        int total = BH;
        init_h16<<<(total + 255) / 256, 256, 0, stream>>>(h0, hf);
    }
    {
        void* args[] = {(void*)&seq_dt, (void*)&seq_types, (void*)&c0, (void*)&ct0,
                        (void*)&P2, (void*)&Wt, (void*)&hf, (void*)&flags, (void*)&out};
        hipLaunchCooperativeKernel((void*)hawkes_main, dim3(NBLK), dim3(NTHR),
                                   args, 0, stream);
    }
}